// Round 4
// baseline (8664.241 us; speedup 1.0000x reference)
//
#include <hip/hip_runtime.h>

// LSTM: B=64, T=1024, D=512, H=512. Gate order i,f,g,o.
// Phase A: xW GEMM, f16 MFMA, 128x128 tile, global_load_lds w16, XOR-swizzled LDS
//   (verified r3). Phase B: persistent scan — REVERTED to the proven 3364us
//   topology: 64 WGs = 4 row-groups(16 rows) x 16 slices(32 units), tag-in-data
//   publish (SINGLE agent store), 16-ull agent poll, two barriers.
// One bounded experiment: per-thread STICKY fast poll = plain volatile loads +
//   acquire-agent fence (L1 inv) each iteration; guard 512 then permanent
//   degrade to the proven agent path (worst case ~+20us once per launch).

#define B_  64
#define T_  1024
#define D_  512
#define H_  512
#define G4H 2048

typedef _Float16 half8 __attribute__((ext_vector_type(8)));
typedef _Float16 half4 __attribute__((ext_vector_type(4)));
typedef float    f32x4 __attribute__((ext_vector_type(4)));
typedef unsigned long long ull;
typedef unsigned int u32;

static __device__ __forceinline__ float sigm(float x) { return 1.f / (1.f + __expf(-x)); }
static __device__ __forceinline__ float tanh_(float x) {
    float xc = fminf(fmaxf(x, -15.f), 15.f);
    float e  = __expf(2.f * xc);
    return (e - 1.f) / (e + 1.f);
}
static __device__ __forceinline__ float lo16f(unsigned u) {
    return (float)__builtin_bit_cast(_Float16, (unsigned short)(u & 0xffffu));
}
static __device__ __forceinline__ float hi16f(unsigned u) {
    return (float)__builtin_bit_cast(_Float16, (unsigned short)(u >> 16));
}
static __device__ __forceinline__ void gload_lds16(const _Float16* g, _Float16* l) {
    __builtin_amdgcn_global_load_lds((const __attribute__((address_space(1))) u32*)g,
                                     (__attribute__((address_space(3))) u32*)l, 16, 0, 0);
}

// ---------------- init: transpose-convert [512][2048] f32 -> [2048][512] f16
__global__ void trans_w(const float* __restrict__ W, _Float16* __restrict__ WT) {
    int idx = blockIdx.x * blockDim.x + threadIdx.x;
    int total = D_ * G4H;
    int stride = gridDim.x * blockDim.x;
    for (int i = idx; i < total; i += stride) {
        int k = i >> 11;
        int n = i & (G4H - 1);
        WT[(size_t)n * D_ + k] = (_Float16)W[i];
    }
}

// ---------------- init: x f32 -> f16
__global__ void conv_x(const float* __restrict__ x, _Float16* __restrict__ xh) {
    int idx = blockIdx.x * blockDim.x + threadIdx.x;
    int total = (B_ * T_ * D_) / 4;
    int stride = gridDim.x * blockDim.x;
    const f32x4* xi = (const f32x4*)x;
    half4* xo = (half4*)xh;
    for (int i = idx; i < total; i += stride) {
        f32x4 v = xi[i];
        xo[i] = (half4){(_Float16)v.x, (_Float16)v.y, (_Float16)v.z, (_Float16)v.w};
    }
}

__global__ void zero_buf(unsigned* __restrict__ p, int n) {
    int idx = blockIdx.x * blockDim.x + threadIdx.x;
    int stride = gridDim.x * blockDim.x;
    for (int i = idx; i < n; i += stride) p[i] = 0u;
}

// ---------------- phase A (fast): 128x128 tile, f16 A via precomputed xh (verified r3)
__global__ __launch_bounds__(256) void gemm_xw_f16(const _Float16* __restrict__ xh,
                                                   const _Float16* __restrict__ WkT,
                                                   const float* __restrict__ bias,
                                                   _Float16* __restrict__ xw, int tbase) {
    __shared__ _Float16 As[128 * 64];   // [row][64 k] f16, XOR-swizzled (byte ^= (row&7)<<4)
    __shared__ _Float16 Bs[128 * 64];
    const int tid  = threadIdx.x;
    const int lane = tid & 63;
    const int wave = tid >> 6;
    const int l15  = lane & 15;
    const int quad = lane >> 4;
    const int b     = blockIdx.z;
    const int n0    = blockIdx.x * 128;
    const int tloc0 = blockIdx.y * 128;

    const int srow = tid >> 3;
    const int sseg = tid & 7;

    f32x4 acc[2][8];
#pragma unroll
    for (int rt = 0; rt < 2; ++rt)
#pragma unroll
        for (int ct = 0; ct < 8; ++ct) acc[rt][ct] = (f32x4){0.f, 0.f, 0.f, 0.f};

    const _Float16* abase = xh + ((size_t)b * T_ + tbase + tloc0) * D_;
    const _Float16* bbase = WkT + (size_t)n0 * D_;

    for (int kb = 0; kb < 8; ++kb) {
        __syncthreads();
#pragma unroll
        for (int q = 0; q < 4; ++q) {
            int row  = q * 32 + srow;
            int col2 = (sseg * 16) ^ ((row & 7) << 4);
            _Float16* ldst = (_Float16*)((char*)As + q * 4096 + wave * 1024);
            gload_lds16(abase + (size_t)row * D_ + kb * 64 + (col2 >> 1), ldst);
            _Float16* ldstb = (_Float16*)((char*)Bs + q * 4096 + wave * 1024);
            gload_lds16(bbase + (size_t)row * D_ + kb * 64 + (col2 >> 1), ldstb);
        }
        __syncthreads();
#pragma unroll
        for (int ks = 0; ks < 2; ++ks) {
            half8 af[2];
#pragma unroll
            for (int rt = 0; rt < 2; ++rt) {
                int row = wave * 32 + rt * 16 + l15;
                int c2  = (ks * 64 + quad * 16) ^ ((row & 7) << 4);
                af[rt] = *(const half8*)&As[row * 64 + (c2 >> 1)];
            }
#pragma unroll
            for (int ct = 0; ct < 8; ++ct) {
                int brw = ct * 16 + l15;
                int c2  = (ks * 64 + quad * 16) ^ ((brw & 7) << 4);
                half8 bf = *(const half8*)&Bs[brw * 64 + (c2 >> 1)];
                acc[0][ct] = __builtin_amdgcn_mfma_f32_16x16x32_f16(af[0], bf, acc[0][ct], 0, 0, 0);
                acc[1][ct] = __builtin_amdgcn_mfma_f32_16x16x32_f16(af[1], bf, acc[1][ct], 0, 0, 0);
            }
        }
    }
#pragma unroll
    for (int ct = 0; ct < 8; ++ct) {
        int col = n0 + ct * 16 + l15;
        float bs = bias[col];
#pragma unroll
        for (int rt = 0; rt < 2; ++rt)
#pragma unroll
            for (int r = 0; r < 4; ++r) {
                int tt = tloc0 + wave * 32 + rt * 16 + quad * 4 + r;
                xw[((size_t)tt * B_ + b) * G4H + col] = (_Float16)(acc[rt][ct][r] + bs);
            }
    }
}

// ---------------- phase A (fallback, small ws): 64x64 kernel
__global__ __launch_bounds__(256) void gemm_xw_small(const float* __restrict__ x,
                                                     const _Float16* __restrict__ WkT,
                                                     const float* __restrict__ bias,
                                                     _Float16* __restrict__ xw,
                                                     int tbase) {
    __shared__ _Float16 As[64][40];
    __shared__ _Float16 Bst[64][40];
    const int tid  = threadIdx.x;
    const int lane = tid & 63;
    const int wave = tid >> 6;
    const int l15  = lane & 15;
    const int quad = lane >> 4;
    const int b     = blockIdx.z;
    const int n0    = blockIdx.x * 64;
    const int tloc0 = blockIdx.y * 64;

    const float* xbase = x + ((size_t)b * T_ + (tbase + tloc0)) * D_;
    f32x4 acc[4];
#pragma unroll
    for (int i = 0; i < 4; ++i) acc[i] = (f32x4){0.f, 0.f, 0.f, 0.f};

    const int ai = tid >> 2, ac = tid & 3;
    const int bn = tid >> 2, bq = tid & 3;

    for (int kb = 0; kb < 16; ++kb) {
        __syncthreads();
        const float* ap = xbase + (size_t)ai * D_ + kb * 32 + ac * 8;
        f32x4 av0 = *(const f32x4*)ap;
        f32x4 av1 = *(const f32x4*)(ap + 4);
        half8 ah = { (_Float16)av0.x, (_Float16)av0.y, (_Float16)av0.z, (_Float16)av0.w,
                     (_Float16)av1.x, (_Float16)av1.y, (_Float16)av1.z, (_Float16)av1.w };
        *(half8*)&As[ai][ac * 8] = ah;
        half8 bv = *(const half8*)(WkT + (size_t)(n0 + bn) * D_ + kb * 32 + bq * 8);
        *(half8*)&Bst[bn][bq * 8] = bv;
        __syncthreads();

        half8 afrag = *(const half8*)&As[16 * wave + l15][quad * 8];
#pragma unroll
        for (int nt = 0; nt < 4; ++nt) {
            half8 bfrag = *(const half8*)&Bst[nt * 16 + l15][quad * 8];
            acc[nt] = __builtin_amdgcn_mfma_f32_16x16x32_f16(afrag, bfrag, acc[nt], 0, 0, 0);
        }
    }
#pragma unroll
    for (int nt = 0; nt < 4; ++nt)
#pragma unroll
        for (int r = 0; r < 4; ++r) {
            int tt  = tloc0 + 16 * wave + quad * 4 + r;
            int col = n0 + nt * 16 + l15;
            xw[((size_t)tt * B_ + b) * G4H + col] = (_Float16)(acc[nt][r] + bias[col]);
        }
}

// ---------------- phase B: persistent scan (PROVEN topology, reverted)
// 64 WGs x 256 thr. WG w: group g=w&3 (rows g*16..+15), slice s=w>>2 (units s*32..+31).
// Wave v = gate v, 2 column tiles of 16 (cols v*512 + u0 + 0..31).
// hbuf: 3 slots x [64][512] tagged dwords (lo16 = h f16, hi16 = step+1).
__global__ __launch_bounds__(256, 1) void lstm_scan(const _Float16* __restrict__ xw,
                                                    const float* __restrict__ Wr,
                                                    unsigned* __restrict__ hbuf,
                                                    float* __restrict__ cio,
                                                    float* __restrict__ out,
                                                    int t0, int t1) {
    const int w    = blockIdx.x;
    const int g    = w & 3;
    const int s    = w >> 2;
    const int u0   = s * 32;
    const int tid  = threadIdx.x;
    const int lane = tid & 63;
    const int wave = tid >> 6;
    const int l15  = lane & 15;
    const int quad = lane >> 4;

    // B-frags in registers: wave v = gate v, col tiles ct=0,1. 128 VGPRs.
    half8 bfrag[2][16];
#pragma unroll
    for (int ct = 0; ct < 2; ++ct) {
        const int col = wave * H_ + u0 + ct * 16 + l15;
#pragma unroll
        for (int kt = 0; kt < 16; ++kt) {
            half8 v;
#pragma unroll
            for (int j = 0; j < 8; ++j)
                v[j] = (_Float16)Wr[(size_t)(kt * 32 + quad * 8 + j) * G4H + col];
            bfrag[ct][kt] = v;
        }
    }

    const int rho  = tid >> 4;        // batch-row in group
    const int jj   = tid & 15;        // unit-pair in slice
    const int brow = g * 16 + rho;
    const int un0  = u0 + 2 * jj;     // this thread's two units
    float c0 = 0.f, c1 = 0.f;
    if (t0 != 0) {
        c0 = cio[(size_t)brow * H_ + un0];
        c1 = cio[(size_t)brow * H_ + un0 + 1];
    }

    __shared__ _Float16 hS[16][520];      // group h tile, pad 8 f16
    __shared__ float    zS[16][4][34];    // z exchange

    const size_t slotSz = (size_t)B_ * H_;   // dwords per slot
    bool fastok = true;   // sticky: first fence-path guard trip -> permanent agent polls

    for (int t = t0; t < t1; ++t) {
        // prefetch xw: 4 plain f16-pair dwords, one per gate
        const unsigned* xwd = (const unsigned*)(xw + ((size_t)(t - t0) * B_ + brow) * G4H);
        const int dbase = (u0 >> 1) + jj;
        unsigned xwi = xwd[0 * 256 + dbase];
        unsigned xwf = xwd[1 * 256 + dbase];
        unsigned xwg = xwd[2 * 256 + dbase];
        unsigned xwo = xwd[3 * 256 + dbase];

        if (t > 0) {
            // poll tagged h data: thread covers units 2*tid,2*tid+1 for all 16 rows
            const ull* src = (const ull*)(hbuf + (size_t)((t - 1) % 3) * slotSz)
                             + (size_t)(g * 16) * 256 + tid;
            const unsigned tgt = (unsigned)(t & 0xffff);
            const ull expect = ((ull)tgt << 16) | ((ull)tgt << 48);
            ull v[16];
            bool got = false;
            if (fastok) {
                // EXPERIMENT: plain loads + acquire-agent fence (L1 inv) per iteration.
                // If the publish's value is servable from this XCD's L2, detection RTT
                // drops ~4x. Tag-in-data => any match is valid regardless of cache path.
                int guard = 0;
                while (true) {
                    __builtin_amdgcn_fence(__ATOMIC_ACQUIRE, "agent");
                    ull diff = 0;
#pragma unroll
                    for (int k = 0; k < 16; ++k)
                        v[k] = ((const volatile ull*)src)[(size_t)k * 256];
#pragma unroll
                    for (int k = 0; k < 16; ++k)
                        diff |= (v[k] ^ expect) & 0xffff0000ffff0000ull;
                    if (diff == 0) { got = true; break; }
                    if (++guard > 512) { fastok = false; break; }   // sticky degrade
                }
            }
            if (!got) {
                int guard = 0;
                while (true) {
                    ull diff = 0;
#pragma unroll
                    for (int k = 0; k < 16; ++k)
                        v[k] = __hip_atomic_load(src + (size_t)k * 256,
                                                 __ATOMIC_RELAXED, __HIP_MEMORY_SCOPE_AGENT);
#pragma unroll
                    for (int k = 0; k < 16; ++k)
                        diff |= (v[k] ^ expect) & 0xffff0000ffff0000ull;
                    if (diff == 0) break;
                    if (++guard > 8192) break;   // bailout: visible failure, not a hang
                }
            }
            // strip tags, pack 2 f16 -> dword, stage to LDS
#pragma unroll
            for (int k = 0; k < 16; ++k) {
                unsigned p = (unsigned)(v[k] & 0xffffu) | (((unsigned)(v[k] >> 32)) << 16);
                *(unsigned*)&hS[k][2 * tid] = p;
            }
        }
        __syncthreads();   // BARRIER1: hS staged (also protects hS vs prev-step readers)

        f32x4 a0 = {0.f,0.f,0.f,0.f}, a1 = a0, b0 = a0, b1 = a0;
        if (t > 0) {
#pragma unroll
            for (int kt = 0; kt < 16; kt += 2) {
                half8 af0 = *(const half8*)&hS[l15][kt * 32 + quad * 8];
                half8 af1 = *(const half8*)&hS[l15][(kt + 1) * 32 + quad * 8];
                a0 = __builtin_amdgcn_mfma_f32_16x16x32_f16(af0, bfrag[0][kt],     a0, 0, 0, 0);
                a1 = __builtin_amdgcn_mfma_f32_16x16x32_f16(af0, bfrag[1][kt],     a1, 0, 0, 0);
                b0 = __builtin_amdgcn_mfma_f32_16x16x32_f16(af1, bfrag[0][kt + 1], b0, 0, 0, 0);
                b1 = __builtin_amdgcn_mfma_f32_16x16x32_f16(af1, bfrag[1][kt + 1], b1, 0, 0, 0);
            }
        }
        f32x4 z0 = a0 + b0, z1 = a1 + b1;
#pragma unroll
        for (int r = 0; r < 4; ++r) {
            zS[quad * 4 + r][wave][l15]      = z0[r];
            zS[quad * 4 + r][wave][16 + l15] = z1[r];
        }
        __syncthreads();   // BARRIER2: zS ready

        float zi0 = zS[rho][0][2*jj] + lo16f(xwi), zi1 = zS[rho][0][2*jj+1] + hi16f(xwi);
        float zf0 = zS[rho][1][2*jj] + lo16f(xwf), zf1 = zS[rho][1][2*jj+1] + hi16f(xwf);
        float zg0 = zS[rho][2][2*jj] + lo16f(xwg), zg1 = zS[rho][2][2*jj+1] + hi16f(xwg);
        float zo0 = zS[rho][3][2*jj] + lo16f(xwo), zo1 = zS[rho][3][2*jj+1] + hi16f(xwo);

        c0 = sigm(zf0) * c0 + sigm(zi0) * tanh_(zg0);
        c1 = sigm(zf1) * c1 + sigm(zi1) * tanh_(zg1);
        float h0 = sigm(zo0) * tanh_(c0);
        float h1 = sigm(zo1) * tanh_(c1);

        // tagged publish: ONE 8B relaxed agent store (proven protocol)
        const unsigned tagw = ((unsigned)((t + 1) & 0xffff)) << 16;
        unsigned d0 = (unsigned)__builtin_bit_cast(unsigned short, (_Float16)h0) | tagw;
        unsigned d1 = (unsigned)__builtin_bit_cast(unsigned short, (_Float16)h1) | tagw;
        ull wv = (ull)d0 | ((ull)d1 << 32);
        __hip_atomic_store((ull*)(hbuf + (size_t)(t % 3) * slotSz) + (size_t)brow * 256 + (un0 >> 1),
                           wv, __ATOMIC_RELAXED, __HIP_MEMORY_SCOPE_AGENT);

        if (t == T_ - 1) {
            out[(size_t)brow * H_ + un0]     = h0;
            out[(size_t)brow * H_ + un0 + 1] = h1;
        }
    }
    cio[(size_t)brow * H_ + un0]     = c0;
    cio[(size_t)brow * H_ + un0 + 1] = c1;
}

// ---------------- launch
extern "C" void kernel_launch(void* const* d_in, const int* in_sizes, int n_in,
                              void* d_out, int out_size, void* d_ws, size_t ws_size,
                              hipStream_t stream) {
    (void)in_sizes; (void)n_in;
    const float* x    = (const float*)d_in[0];
    const float* Wk   = (const float*)d_in[1];
    const float* Wr   = (const float*)d_in[2];
    const float* bias = (const float*)d_in[3];
    float* out = (float*)d_out;

    char* ws = (char*)d_ws;
    _Float16* WkT  = (_Float16*)(ws + 1024);                      // 2 MB
    unsigned* hbuf = (unsigned*)(ws + 1024 + 2097152);            // 384 KB (3 slots)
    float*    cio  = (float*)(ws + 1024 + 2097152 + 393216);      // 128 KB
    const size_t fixed   = 1024 + 2097152 + 393216 + 131072;
    const size_t xhBytes = (size_t)B_ * T_ * D_ * 2;              // 64 MB
    const size_t perT    = (size_t)B_ * G4H * 2;                  // 256 KB per timestep

    size_t avail = (ws_size > fixed) ? ws_size - fixed : 0;
    bool use_xh = avail >= xhBytes + 128 * perT;
    _Float16* xh = (_Float16*)(ws + fixed);
    _Float16* xw = (_Float16*)(ws + fixed + (use_xh ? xhBytes : 0));

    int ct = 0;
    if (use_xh) {
        const int cands[4] = {1024, 512, 256, 128};
        size_t av2 = avail - xhBytes;
        for (int i = 0; i < 4; ++i)
            if ((size_t)cands[i] * perT <= av2) { ct = cands[i]; break; }
    } else {
        const int cands[5] = {1024, 512, 256, 128, 64};
        for (int i = 0; i < 5; ++i)
            if ((size_t)cands[i] * perT <= avail) { ct = cands[i]; break; }
    }
    if (ct == 0) {
        hipMemsetAsync(d_out, 0, (size_t)out_size * 4, stream);
        return;
    }

    zero_buf<<<96, 256, 0, stream>>>(hbuf, 3 * B_ * H_);
    trans_w<<<512, 256, 0, stream>>>(Wk, WkT);
    if (use_xh) conv_x<<<2048, 256, 0, stream>>>(x, xh);

    for (int t0 = 0; t0 < T_; t0 += ct) {
        if (use_xh)
            gemm_xw_f16<<<dim3(16, ct / 128, B_), 256, 0, stream>>>(xh, WkT, bias, xw, t0);
        else
            gemm_xw_small<<<dim3(32, ct / 64, B_), 256, 0, stream>>>(x, WkT, bias, xw, t0);
        lstm_scan<<<64, 256, 0, stream>>>(xw, Wr, hbuf, cio, out, t0, t0 + ct);
    }
}

// Round 5
// 3167.042 us; speedup vs baseline: 2.7358x; 2.7358x over previous
//
#include <hip/hip_runtime.h>

// LSTM: B=64, T=1024, D=512, H=512. Gate order i,f,g,o.
// Phase A: xW GEMM, f16 MFMA, 128x128 tile, global_load_lds w16, XOR-swizzled LDS
//   (verified r3/r4). Phase B: persistent scan — PROVEN 3364us topology, verbatim:
//   64 WGs = 4 row-groups(16 rows) x 16 slices(32 units), tag-in-data publish
//   (single agent store), 16-ull agent-scope poll, two barriers. NO fast-path
//   experiments (sc0 failed r1/r3; acquire-fence poisoned caches r4).
//   bfrag loads from pre-transposed f16 WrT (contiguous b128; verified r3).

#define B_  64
#define T_  1024
#define D_  512
#define H_  512
#define G4H 2048

typedef _Float16 half8 __attribute__((ext_vector_type(8)));
typedef _Float16 half4 __attribute__((ext_vector_type(4)));
typedef float    f32x4 __attribute__((ext_vector_type(4)));
typedef unsigned long long ull;
typedef unsigned int u32;

static __device__ __forceinline__ float sigm(float x) { return 1.f / (1.f + __expf(-x)); }
static __device__ __forceinline__ float tanh_(float x) {
    float xc = fminf(fmaxf(x, -15.f), 15.f);
    float e  = __expf(2.f * xc);
    return (e - 1.f) / (e + 1.f);
}
static __device__ __forceinline__ float lo16f(unsigned u) {
    return (float)__builtin_bit_cast(_Float16, (unsigned short)(u & 0xffffu));
}
static __device__ __forceinline__ float hi16f(unsigned u) {
    return (float)__builtin_bit_cast(_Float16, (unsigned short)(u >> 16));
}
static __device__ __forceinline__ void gload_lds16(const _Float16* g, _Float16* l) {
    __builtin_amdgcn_global_load_lds((const __attribute__((address_space(1))) u32*)g,
                                     (__attribute__((address_space(3))) u32*)l, 16, 0, 0);
}

// ---------------- init: transpose-convert [512][2048] f32 -> [2048][512] f16
__global__ void trans_w(const float* __restrict__ W, _Float16* __restrict__ WT) {
    int idx = blockIdx.x * blockDim.x + threadIdx.x;
    int total = D_ * G4H;
    int stride = gridDim.x * blockDim.x;
    for (int i = idx; i < total; i += stride) {
        int k = i >> 11;
        int n = i & (G4H - 1);
        WT[(size_t)n * D_ + k] = (_Float16)W[i];
    }
}

// ---------------- init: x f32 -> f16
__global__ void conv_x(const float* __restrict__ x, _Float16* __restrict__ xh) {
    int idx = blockIdx.x * blockDim.x + threadIdx.x;
    int total = (B_ * T_ * D_) / 4;
    int stride = gridDim.x * blockDim.x;
    const f32x4* xi = (const f32x4*)x;
    half4* xo = (half4*)xh;
    for (int i = idx; i < total; i += stride) {
        f32x4 v = xi[i];
        xo[i] = (half4){(_Float16)v.x, (_Float16)v.y, (_Float16)v.z, (_Float16)v.w};
    }
}

__global__ void zero_buf(unsigned* __restrict__ p, int n) {
    int idx = blockIdx.x * blockDim.x + threadIdx.x;
    int stride = gridDim.x * blockDim.x;
    for (int i = idx; i < n; i += stride) p[i] = 0u;
}

// ---------------- phase A (fast): 128x128 tile, f16 A via precomputed xh (verified)
__global__ __launch_bounds__(256) void gemm_xw_f16(const _Float16* __restrict__ xh,
                                                   const _Float16* __restrict__ WkT,
                                                   const float* __restrict__ bias,
                                                   _Float16* __restrict__ xw, int tbase) {
    __shared__ _Float16 As[128 * 64];   // [row][64 k] f16, XOR-swizzled (byte ^= (row&7)<<4)
    __shared__ _Float16 Bs[128 * 64];
    const int tid  = threadIdx.x;
    const int lane = tid & 63;
    const int wave = tid >> 6;
    const int l15  = lane & 15;
    const int quad = lane >> 4;
    const int b     = blockIdx.z;
    const int n0    = blockIdx.x * 128;
    const int tloc0 = blockIdx.y * 128;

    const int srow = tid >> 3;
    const int sseg = tid & 7;

    f32x4 acc[2][8];
#pragma unroll
    for (int rt = 0; rt < 2; ++rt)
#pragma unroll
        for (int ct = 0; ct < 8; ++ct) acc[rt][ct] = (f32x4){0.f, 0.f, 0.f, 0.f};

    const _Float16* abase = xh + ((size_t)b * T_ + tbase + tloc0) * D_;
    const _Float16* bbase = WkT + (size_t)n0 * D_;

    for (int kb = 0; kb < 8; ++kb) {
        __syncthreads();
#pragma unroll
        for (int q = 0; q < 4; ++q) {
            int row  = q * 32 + srow;
            int col2 = (sseg * 16) ^ ((row & 7) << 4);
            _Float16* ldst = (_Float16*)((char*)As + q * 4096 + wave * 1024);
            gload_lds16(abase + (size_t)row * D_ + kb * 64 + (col2 >> 1), ldst);
            _Float16* ldstb = (_Float16*)((char*)Bs + q * 4096 + wave * 1024);
            gload_lds16(bbase + (size_t)row * D_ + kb * 64 + (col2 >> 1), ldstb);
        }
        __syncthreads();
#pragma unroll
        for (int ks = 0; ks < 2; ++ks) {
            half8 af[2];
#pragma unroll
            for (int rt = 0; rt < 2; ++rt) {
                int row = wave * 32 + rt * 16 + l15;
                int c2  = (ks * 64 + quad * 16) ^ ((row & 7) << 4);
                af[rt] = *(const half8*)&As[row * 64 + (c2 >> 1)];
            }
#pragma unroll
            for (int ct = 0; ct < 8; ++ct) {
                int brw = ct * 16 + l15;
                int c2  = (ks * 64 + quad * 16) ^ ((brw & 7) << 4);
                half8 bf = *(const half8*)&Bs[brw * 64 + (c2 >> 1)];
                acc[0][ct] = __builtin_amdgcn_mfma_f32_16x16x32_f16(af[0], bf, acc[0][ct], 0, 0, 0);
                acc[1][ct] = __builtin_amdgcn_mfma_f32_16x16x32_f16(af[1], bf, acc[1][ct], 0, 0, 0);
            }
        }
    }
#pragma unroll
    for (int ct = 0; ct < 8; ++ct) {
        int col = n0 + ct * 16 + l15;
        float bs = bias[col];
#pragma unroll
        for (int rt = 0; rt < 2; ++rt)
#pragma unroll
            for (int r = 0; r < 4; ++r) {
                int tt = tloc0 + wave * 32 + rt * 16 + quad * 4 + r;
                xw[((size_t)tt * B_ + b) * G4H + col] = (_Float16)(acc[rt][ct][r] + bs);
            }
    }
}

// ---------------- phase A (fallback, small ws): 64x64 kernel
__global__ __launch_bounds__(256) void gemm_xw_small(const float* __restrict__ x,
                                                     const _Float16* __restrict__ WkT,
                                                     const float* __restrict__ bias,
                                                     _Float16* __restrict__ xw,
                                                     int tbase) {
    __shared__ _Float16 As[64][40];
    __shared__ _Float16 Bst[64][40];
    const int tid  = threadIdx.x;
    const int lane = tid & 63;
    const int wave = tid >> 6;
    const int l15  = lane & 15;
    const int quad = lane >> 4;
    const int b     = blockIdx.z;
    const int n0    = blockIdx.x * 64;
    const int tloc0 = blockIdx.y * 64;

    const float* xbase = x + ((size_t)b * T_ + (tbase + tloc0)) * D_;
    f32x4 acc[4];
#pragma unroll
    for (int i = 0; i < 4; ++i) acc[i] = (f32x4){0.f, 0.f, 0.f, 0.f};

    const int ai = tid >> 2, ac = tid & 3;
    const int bn = tid >> 2, bq = tid & 3;

    for (int kb = 0; kb < 16; ++kb) {
        __syncthreads();
        const float* ap = xbase + (size_t)ai * D_ + kb * 32 + ac * 8;
        f32x4 av0 = *(const f32x4*)ap;
        f32x4 av1 = *(const f32x4*)(ap + 4);
        half8 ah = { (_Float16)av0.x, (_Float16)av0.y, (_Float16)av0.z, (_Float16)av0.w,
                     (_Float16)av1.x, (_Float16)av1.y, (_Float16)av1.z, (_Float16)av1.w };
        *(half8*)&As[ai][ac * 8] = ah;
        half8 bv = *(const half8*)(WkT + (size_t)(n0 + bn) * D_ + kb * 32 + bq * 8);
        *(half8*)&Bst[bn][bq * 8] = bv;
        __syncthreads();

        half8 afrag = *(const half8*)&As[16 * wave + l15][quad * 8];
#pragma unroll
        for (int nt = 0; nt < 4; ++nt) {
            half8 bfrag = *(const half8*)&Bst[nt * 16 + l15][quad * 8];
            acc[nt] = __builtin_amdgcn_mfma_f32_16x16x32_f16(afrag, bfrag, acc[nt], 0, 0, 0);
        }
    }
#pragma unroll
    for (int nt = 0; nt < 4; ++nt)
#pragma unroll
        for (int r = 0; r < 4; ++r) {
            int tt  = tloc0 + 16 * wave + quad * 4 + r;
            int col = n0 + nt * 16 + l15;
            xw[((size_t)tt * B_ + b) * G4H + col] = (_Float16)(acc[nt][r] + bias[col]);
        }
}

// ---------------- phase B: persistent scan (PROVEN topology — no experiments)
// 64 WGs x 256 thr. WG w: group g=w&3 (rows g*16..+15), slice s=w>>2 (units s*32..+31).
// Wave v = gate v, 2 column tiles of 16 (cols v*512 + u0 + 0..31).
// hbuf: 3 slots x [64][512] tagged dwords (lo16 = h f16, hi16 = step+1).
__global__ __launch_bounds__(256, 1) void lstm_scan(const _Float16* __restrict__ xw,
                                                    const _Float16* __restrict__ WrT,
                                                    unsigned* __restrict__ hbuf,
                                                    float* __restrict__ cio,
                                                    float* __restrict__ out,
                                                    int t0, int t1) {
    const int w    = blockIdx.x;
    const int g    = w & 3;
    const int s    = w >> 2;
    const int u0   = s * 32;
    const int tid  = threadIdx.x;
    const int lane = tid & 63;
    const int wave = tid >> 6;
    const int l15  = lane & 15;
    const int quad = lane >> 4;

    // B-frags in registers: wave v = gate v, col tiles ct=0,1. 128 VGPRs.
    // Contiguous b128 loads from pre-transposed f16 WrT (verified r3).
    half8 bfrag[2][16];
#pragma unroll
    for (int ct = 0; ct < 2; ++ct) {
        const int col = wave * H_ + u0 + ct * 16 + l15;
        const _Float16* wp = WrT + (size_t)col * D_;
#pragma unroll
        for (int kt = 0; kt < 16; ++kt)
            bfrag[ct][kt] = *(const half8*)(wp + kt * 32 + quad * 8);
    }

    const int rho  = tid >> 4;        // batch-row in group
    const int jj   = tid & 15;        // unit-pair in slice
    const int brow = g * 16 + rho;
    const int un0  = u0 + 2 * jj;     // this thread's two units
    float c0 = 0.f, c1 = 0.f;
    if (t0 != 0) {
        c0 = cio[(size_t)brow * H_ + un0];
        c1 = cio[(size_t)brow * H_ + un0 + 1];
    }

    __shared__ _Float16 hS[16][520];      // group h tile, pad 8 f16
    __shared__ float    zS[16][4][34];    // z exchange

    const size_t slotSz = (size_t)B_ * H_;   // dwords per slot

    for (int t = t0; t < t1; ++t) {
        // prefetch xw: 4 plain f16-pair dwords, one per gate
        const unsigned* xwd = (const unsigned*)(xw + ((size_t)(t - t0) * B_ + brow) * G4H);
        const int dbase = (u0 >> 1) + jj;
        unsigned xwi = xwd[0 * 256 + dbase];
        unsigned xwf = xwd[1 * 256 + dbase];
        unsigned xwg = xwd[2 * 256 + dbase];
        unsigned xwo = xwd[3 * 256 + dbase];

        if (t > 0) {
            // poll tagged h data directly: thread covers units 2*tid,2*tid+1 for all 16 rows
            const ull* src = (const ull*)(hbuf + (size_t)((t - 1) % 3) * slotSz)
                             + (size_t)(g * 16) * 256 + tid;
            const unsigned tgt = (unsigned)(t & 0xffff);
            const ull expect = ((ull)tgt << 16) | ((ull)tgt << 48);
            ull v[16];
            int guard = 0;
            while (true) {
                ull diff = 0;
#pragma unroll
                for (int k = 0; k < 16; ++k)
                    v[k] = __hip_atomic_load(src + (size_t)k * 256,
                                             __ATOMIC_RELAXED, __HIP_MEMORY_SCOPE_AGENT);
#pragma unroll
                for (int k = 0; k < 16; ++k)
                    diff |= (v[k] ^ expect) & 0xffff0000ffff0000ull;
                if (diff == 0) break;
                if (++guard > 8192) break;   // bailout: visible failure, not a hang
            }
            // strip tags, pack 2 f16 -> dword, stage to LDS
#pragma unroll
            for (int k = 0; k < 16; ++k) {
                unsigned p = (unsigned)(v[k] & 0xffffu) | (((unsigned)(v[k] >> 32)) << 16);
                *(unsigned*)&hS[k][2 * tid] = p;
            }
        }
        __syncthreads();   // BARRIER1: hS staged (also protects hS vs prev-step readers)

        f32x4 a0 = {0.f,0.f,0.f,0.f}, a1 = a0, b0 = a0, b1 = a0;
        if (t > 0) {
#pragma unroll
            for (int kt = 0; kt < 16; kt += 2) {
                half8 af0 = *(const half8*)&hS[l15][kt * 32 + quad * 8];
                half8 af1 = *(const half8*)&hS[l15][(kt + 1) * 32 + quad * 8];
                a0 = __builtin_amdgcn_mfma_f32_16x16x32_f16(af0, bfrag[0][kt],     a0, 0, 0, 0);
                a1 = __builtin_amdgcn_mfma_f32_16x16x32_f16(af0, bfrag[1][kt],     a1, 0, 0, 0);
                b0 = __builtin_amdgcn_mfma_f32_16x16x32_f16(af1, bfrag[0][kt + 1], b0, 0, 0, 0);
                b1 = __builtin_amdgcn_mfma_f32_16x16x32_f16(af1, bfrag[1][kt + 1], b1, 0, 0, 0);
            }
        }
        f32x4 z0 = a0 + b0, z1 = a1 + b1;
#pragma unroll
        for (int r = 0; r < 4; ++r) {
            zS[quad * 4 + r][wave][l15]      = z0[r];
            zS[quad * 4 + r][wave][16 + l15] = z1[r];
        }
        __syncthreads();   // BARRIER2: zS ready

        float zi0 = zS[rho][0][2*jj] + lo16f(xwi), zi1 = zS[rho][0][2*jj+1] + hi16f(xwi);
        float zf0 = zS[rho][1][2*jj] + lo16f(xwf), zf1 = zS[rho][1][2*jj+1] + hi16f(xwf);
        float zg0 = zS[rho][2][2*jj] + lo16f(xwg), zg1 = zS[rho][2][2*jj+1] + hi16f(xwg);
        float zo0 = zS[rho][3][2*jj] + lo16f(xwo), zo1 = zS[rho][3][2*jj+1] + hi16f(xwo);

        c0 = sigm(zf0) * c0 + sigm(zi0) * tanh_(zg0);
        c1 = sigm(zf1) * c1 + sigm(zi1) * tanh_(zg1);
        float h0 = sigm(zo0) * tanh_(c0);
        float h1 = sigm(zo1) * tanh_(c1);

        // tagged publish: ONE 8B relaxed agent store (proven protocol)
        const unsigned tagw = ((unsigned)((t + 1) & 0xffff)) << 16;
        unsigned d0 = (unsigned)__builtin_bit_cast(unsigned short, (_Float16)h0) | tagw;
        unsigned d1 = (unsigned)__builtin_bit_cast(unsigned short, (_Float16)h1) | tagw;
        ull wv = (ull)d0 | ((ull)d1 << 32);
        __hip_atomic_store((ull*)(hbuf + (size_t)(t % 3) * slotSz) + (size_t)brow * 256 + (un0 >> 1),
                           wv, __ATOMIC_RELAXED, __HIP_MEMORY_SCOPE_AGENT);

        if (t == T_ - 1) {
            out[(size_t)brow * H_ + un0]     = h0;
            out[(size_t)brow * H_ + un0 + 1] = h1;
        }
    }
    cio[(size_t)brow * H_ + un0]     = c0;
    cio[(size_t)brow * H_ + un0 + 1] = c1;
}

// ---------------- launch
extern "C" void kernel_launch(void* const* d_in, const int* in_sizes, int n_in,
                              void* d_out, int out_size, void* d_ws, size_t ws_size,
                              hipStream_t stream) {
    (void)in_sizes; (void)n_in;
    const float* x    = (const float*)d_in[0];
    const float* Wk   = (const float*)d_in[1];
    const float* Wr   = (const float*)d_in[2];
    const float* bias = (const float*)d_in[3];
    float* out = (float*)d_out;

    char* ws = (char*)d_ws;
    _Float16* WkT  = (_Float16*)(ws + 1024);                      // 2 MB
    _Float16* WrT  = (_Float16*)(ws + 1024 + 2097152);            // 2 MB
    unsigned* hbuf = (unsigned*)(ws + 1024 + 2 * 2097152);        // 384 KB (3 slots)
    float*    cio  = (float*)(ws + 1024 + 2 * 2097152 + 393216);  // 128 KB
    const size_t fixed   = 1024 + 2 * 2097152 + 393216 + 131072;
    const size_t xhBytes = (size_t)B_ * T_ * D_ * 2;              // 64 MB
    const size_t perT    = (size_t)B_ * G4H * 2;                  // 256 KB per timestep

    size_t avail = (ws_size > fixed) ? ws_size - fixed : 0;
    bool use_xh = avail >= xhBytes + 128 * perT;
    _Float16* xh = (_Float16*)(ws + fixed);
    _Float16* xw = (_Float16*)(ws + fixed + (use_xh ? xhBytes : 0));

    int ct = 0;
    if (use_xh) {
        const int cands[4] = {1024, 512, 256, 128};
        size_t av2 = avail - xhBytes;
        for (int i = 0; i < 4; ++i)
            if ((size_t)cands[i] * perT <= av2) { ct = cands[i]; break; }
    } else {
        const int cands[5] = {1024, 512, 256, 128, 64};
        for (int i = 0; i < 5; ++i)
            if ((size_t)cands[i] * perT <= avail) { ct = cands[i]; break; }
    }
    if (ct == 0) {
        hipMemsetAsync(d_out, 0, (size_t)out_size * 4, stream);
        return;
    }

    zero_buf<<<96, 256, 0, stream>>>(hbuf, 3 * B_ * H_);
    trans_w<<<512, 256, 0, stream>>>(Wk, WkT);
    trans_w<<<512, 256, 0, stream>>>(Wr, WrT);
    if (use_xh) conv_x<<<2048, 256, 0, stream>>>(x, xh);

    for (int t0 = 0; t0 < T_; t0 += ct) {
        if (use_xh)
            gemm_xw_f16<<<dim3(16, ct / 128, B_), 256, 0, stream>>>(xh, WkT, bias, xw, t0);
        else
            gemm_xw_small<<<dim3(32, ct / 64, B_), 256, 0, stream>>>(x, WkT, bias, xw, t0);
        lstm_scan<<<64, 256, 0, stream>>>(xw, WrT, hbuf, cio, out, t0, t0 + ct);
    }
}